// Round 5
// baseline (857.953 us; speedup 1.0000x reference)
//
#include <hip/hip_runtime.h>
#include <hip/hip_bf16.h>
#include <stdint.h>

typedef __bf16 bf16x8  __attribute__((ext_vector_type(8)));
typedef float  f32x16  __attribute__((ext_vector_type(16)));
typedef unsigned short u16;

__device__ __forceinline__ u16 f2bf(float f) {
    return __builtin_bit_cast(u16, __float2bfloat16(f));
}

__device__ __forceinline__ void gload16(const void* g, void* l) {
    __builtin_amdgcn_global_load_lds(
        (const __attribute__((address_space(1))) void*)g,
        (__attribute__((address_space(3))) void*)l,
        16, 0, 0);
}

// ---------------- quantization pipeline ----------------

__global__ void zero3_k(unsigned int* p) {
    if (threadIdx.x < 3) p[threadIdx.x] = 0u;
}

__global__ void maxabs_k(const float* __restrict__ w, int n, unsigned int* __restrict__ out) {
    const int tid = threadIdx.x;
    float m = 0.f;
    for (int i = blockIdx.x * blockDim.x + tid; i < n; i += gridDim.x * blockDim.x)
        m = fmaxf(m, fabsf(w[i]));
    #pragma unroll
    for (int off = 32; off > 0; off >>= 1)
        m = fmaxf(m, __shfl_down(m, off));
    __shared__ float red[4];
    if ((tid & 63) == 0) red[tid >> 6] = m;
    __syncthreads();
    if (tid == 0) {
        m = fmaxf(fmaxf(red[0], red[1]), fmaxf(red[2], red[3]));
        atomicMax(out, __float_as_uint(m));  // all values >=0: uint order == float order
    }
}

// w_q = clip(rint(w/scale), -n, n) * scale, scale = max|w|/n  (all fp32, matches jnp)
__global__ void quant_k(const float* __restrict__ w, int n,
                        const unsigned int* __restrict__ maxbits, float qn,
                        u16* __restrict__ out) {
    const float scale = __uint_as_float(*maxbits) / qn;
    for (int i = blockIdx.x * blockDim.x + threadIdx.x; i < n; i += gridDim.x * blockDim.x) {
        float q = rintf(w[i] / scale);          // RNE == jnp.round
        q = fminf(qn, fmaxf(-qn, q));
        out[i] = f2bf(q * scale);
    }
}

__global__ void cvt_k(const float* __restrict__ x, u16* __restrict__ o, long n) {
    const long stride = (long)gridDim.x * blockDim.x * 4;
    for (long i = ((long)blockIdx.x * blockDim.x + threadIdx.x) * 4; i < n; i += stride) {
        float4 v = *(const float4*)(x + i);
        unsigned int lo = (unsigned int)f2bf(v.x) | ((unsigned int)f2bf(v.y) << 16);
        unsigned int hi = (unsigned int)f2bf(v.z) | ((unsigned int)f2bf(v.w) << 16);
        *(uint2*)(o + i) = make_uint2(lo, hi);
    }
}

// ---------------- GEMM: C = A(MxK) * B(NxK)^T + bias, LeakyReLU ----------------
// 256x256 tile, BK=64, 8 waves (2M x 4N), per-wave 128x64 = 4x2 32x32x16 frags.
// ONE s_barrier + one vmcnt(0) per K-64 tile (2-deep LDS ring; stage(k+1) is
// issued after the tile-k head barrier, which certifies all waves drained
// tile-(k-1)'s reads of the same buffer -> race-free with a single barrier).
// Within a tile: 4 K=16 quarters, register-double-buffered frag sets; each
// quarter's reads issue under the previous quarter's MFMA (lgkmcnt(0)+
// sched_barrier pairs, rule 18). Swizzle: 16B-granule g ^= row&7 on [256][64]
// bf16 tiles (2-way residual = free). setprio around MFMA clusters,
// XCD-bijective block swizzle, LDS-transpose coalesced epilogue.

#define RDQ(AS, BS, q)                                                          \
  do {                                                                          \
    _Pragma("unroll") for (int mi = 0; mi < 4; ++mi)                            \
        AS[mi] = *(const bf16x8*)(sA + arowE + mi * 2048 +                      \
                                  ((((q) * 2 + ls5) ^ l7) << 3));               \
    _Pragma("unroll") for (int ni = 0; ni < 2; ++ni)                            \
        BS[ni] = *(const bf16x8*)(sB + browE + ni * 2048 +                      \
                                  ((((q) * 2 + ls5) ^ l7) << 3));               \
  } while (0)

#define MFMA_Q(AS, BS)                                                          \
  do {                                                                          \
    __builtin_amdgcn_s_setprio(1);                                              \
    _Pragma("unroll") for (int mi = 0; mi < 4; ++mi)                            \
      _Pragma("unroll") for (int ni = 0; ni < 2; ++ni)                          \
        acc[mi][ni] = __builtin_amdgcn_mfma_f32_32x32x16_bf16(                  \
            AS[mi], BS[ni], acc[mi][ni], 0, 0, 0);                              \
    __builtin_amdgcn_s_setprio(0);                                              \
  } while (0)

#define LGKM0_SB                                                                \
  asm volatile("s_waitcnt lgkmcnt(0)" ::: "memory");                            \
  __builtin_amdgcn_sched_barrier(0)

#define STAGE(kt)                                                               \
  do {                                                                          \
    const size_t _gk = (size_t)(kt) * 64;                                       \
    _Pragma("unroll") for (int i = 0; i < 4; ++i) {                             \
      gload16(gAs + (size_t)i * 64 * K + _gk,                                   \
              &smem[(kt) & 1][0][i * 4096 + wave * 512]);                       \
      gload16(gBs + (size_t)i * 64 * K + _gk,                                   \
              &smem[(kt) & 1][1][i * 4096 + wave * 512]);                       \
    }                                                                           \
  } while (0)

#define TILE(kt, DO_STAGE)                                                      \
  do {                                                                          \
    asm volatile("s_waitcnt vmcnt(0)" ::: "memory");   /* stage(kt) landed */   \
    __builtin_amdgcn_s_barrier();                      /* buf ready; k-1 done */\
    if (DO_STAGE) STAGE((kt) + 1);                                              \
    const u16* sA = &smem[(kt) & 1][0][0];                                      \
    const u16* sB = &smem[(kt) & 1][1][0];                                      \
    RDQ(a0f, b0f, 0);                                                           \
    LGKM0_SB;                                                                   \
    RDQ(a1f, b1f, 1);                                                           \
    __builtin_amdgcn_sched_barrier(0);                                          \
    MFMA_Q(a0f, b0f);                     /* q0, overlaps q1 reads */           \
    LGKM0_SB;                                                                   \
    RDQ(a0f, b0f, 2);                                                           \
    __builtin_amdgcn_sched_barrier(0);                                          \
    MFMA_Q(a1f, b1f);                     /* q1, overlaps q2 reads */           \
    LGKM0_SB;                                                                   \
    RDQ(a1f, b1f, 3);                                                           \
    __builtin_amdgcn_sched_barrier(0);                                          \
    MFMA_Q(a0f, b0f);                     /* q2, overlaps q3 reads */           \
    LGKM0_SB;                                                                   \
    MFMA_Q(a1f, b1f);                     /* q3 */                              \
  } while (0)

template<int BF16OUT>
__global__ __launch_bounds__(512, 2)
void gemm8p(const u16* __restrict__ A, const u16* __restrict__ B,
            const float* __restrict__ bias, void* __restrict__ Cv,
            int M, int Nn, int K)
{
    __shared__ __align__(128) u16 smem[2][2][16384];  // [ring][A|B][256 rows x 64 cols]

    const int tid  = threadIdx.x;
    const int lane = tid & 63;
    const int wave = tid >> 6;
    const int wm = wave >> 2;   // 0..1 -> row offset wm*128
    const int wn = wave & 3;    // 0..3 -> col offset wn*64
    const int ls5 = lane >> 5;
    const int l7  = lane & 7;

    // XCD-aware bijective swizzle (gridDim.x % 8 == 0 here)
    const int nbx = Nn >> 8;
    const int cpx = gridDim.x >> 3;
    const int bid = blockIdx.x;
    const int swz = (bid & 7) * cpx + (bid >> 3);
    const int bn = (swz % nbx) << 8;
    const int bm = (swz / nbx) << 8;

    // staging: thread t -> LDS row t/8 (+ i*64 per issue), 16B granule t%8;
    // source granule pre-swizzled: g_src = (t%8) ^ (row&7)   (rule 21)
    const int sr = tid >> 3;
    const int scol = (((tid & 7) ^ (sr & 7)) << 3);
    const u16* gAs = A + (size_t)(bm + sr) * K + scol;
    const u16* gBs = B + (size_t)(bn + sr) * K + scol;

    // frag ds_read offsets (u16 elems): row*64 + ((q*2 + ls5) ^ (row&7))*8
    // frag rows = base(mult of 32) + (lane&31) -> row&7 == lane&7 == l7
    const int arowE = (wm * 128 + (lane & 31)) * 64;   // + mi*2048 per m-frag
    const int browE = (wn * 64  + (lane & 31)) * 64;   // + ni*2048 per n-frag

    f32x16 acc[4][2] = {};
    bf16x8 a0f[4], b0f[2], a1f[4], b1f[2];

    STAGE(0);
    const int NT = K >> 6;                 // 16 or 32 (even; epilogue relies on it)
    for (int kt = 0; kt < NT - 1; ++kt)
        TILE(kt, true);
    TILE(NT - 1, false);

    // ---- coalesced epilogue through LDS (per-wave private slice) ----
    // C/D frag layout (m74/m101): col = lane&31, row = (reg&3)+8*(reg>>2)+4*(lane>>5)
    // NT even -> last tile read buf1; lsw lives in buf0. Barrier for safety.
    __builtin_amdgcn_s_barrier();
    float* lsw = (float*)&smem[0][0][0] + wave * (32 * 33);   // 4224B per wave
    const int ecol = lane & 31;
    const int ehi  = lane >> 5;
    const float bv0 = bias[bn + wn * 64 + ecol];
    const float bv1 = bias[bn + wn * 64 + 32 + ecol];
    const int rrow = lane & 31;            // gather: lane -> row, 16-col group
    const int rcg  = lane >> 5;

    #pragma unroll
    for (int mi = 0; mi < 4; ++mi) {
        #pragma unroll
        for (int ni = 0; ni < 2; ++ni) {
            const float bb = ni ? bv1 : bv0;
            #pragma unroll
            for (int reg = 0; reg < 16; ++reg) {
                const int row = (reg & 3) + 8 * (reg >> 2) + 4 * ehi;
                float v = acc[mi][ni][reg] + bb;
                v = (v >= 0.f) ? v : 0.01f * v;
                lsw[row * 33 + ecol] = v;
            }
            asm volatile("s_waitcnt lgkmcnt(0)" ::: "memory");
            const float* src = lsw + rrow * 33 + rcg * 16;
            const size_t grow = (size_t)(bm + wm * 128 + mi * 32 + rrow);
            const int    gcol = bn + wn * 64 + ni * 32 + rcg * 16;
            if (BF16OUT) {
                u16 tmp[16];
                #pragma unroll
                for (int e = 0; e < 16; ++e) tmp[e] = f2bf(src[e]);
                u16* dst = (u16*)Cv + grow * Nn + gcol;
                *(uint4*)dst       = ((const uint4*)tmp)[0];
                *(uint4*)(dst + 8) = ((const uint4*)tmp)[1];
            } else {
                float* dst = (float*)Cv + grow * Nn + gcol;
                #pragma unroll
                for (int e = 0; e < 4; ++e)
                    ((float4*)dst)[e] = ((const float4*)src)[e];
            }
            asm volatile("" ::: "memory");   // keep chunks ordered (WAR on lsw)
        }
    }
}

// ---------------- launch ----------------

extern "C" void kernel_launch(void* const* d_in, const int* in_sizes, int n_in,
                              void* d_out, int out_size, void* d_ws, size_t ws_size,
                              hipStream_t stream) {
    const float* x  = (const float*)d_in[0];
    const float* W0 = (const float*)d_in[1];
    const float* b0 = (const float*)d_in[2];
    const float* W1 = (const float*)d_in[3];
    const float* b1 = (const float*)d_in[4];
    const float* W2 = (const float*)d_in[5];
    const float* b2 = (const float*)d_in[6];

    const int N = 32768, D0 = 1024, D1 = 2048;

    char* ws = (char*)d_ws;
    u16* xbf = (u16*)ws;  ws += (size_t)N * D0 * 2;
    u16* h0  = (u16*)ws;  ws += (size_t)N * D1 * 2;
    u16* h1  = (u16*)ws;  ws += (size_t)N * D1 * 2;
    u16* w0q = (u16*)ws;  ws += (size_t)D1 * D0 * 2;
    u16* w1q = (u16*)ws;  ws += (size_t)D1 * D1 * 2;
    u16* w2q = (u16*)ws;  ws += (size_t)D1 * D1 * 2;
    unsigned int* scales = (unsigned int*)ws;

    zero3_k<<<1, 64, 0, stream>>>(scales);
    maxabs_k<<<256, 256, 0, stream>>>(W0, D1 * D0, scales + 0);
    maxabs_k<<<256, 256, 0, stream>>>(W1, D1 * D1, scales + 1);
    maxabs_k<<<256, 256, 0, stream>>>(W2, D1 * D1, scales + 2);
    quant_k<<<2048, 256, 0, stream>>>(W0, D1 * D0, scales + 0, 127.f, w0q);
    quant_k<<<2048, 256, 0, stream>>>(W1, D1 * D1, scales + 1, 7.f, w1q);
    quant_k<<<2048, 256, 0, stream>>>(W2, D1 * D1, scales + 2, 7.f, w2q);
    cvt_k<<<4096, 256, 0, stream>>>(x, xbf, (long)N * D0);

    const int blocks = (D1 / 256) * (N / 256);   // 8 * 128 = 1024, %8 == 0
    gemm8p<1><<<blocks, 512, 0, stream>>>(xbf, w0q, b0, h0, N, D1, D0);
    gemm8p<1><<<blocks, 512, 0, stream>>>(h0, w1q, b1, h1, N, D1, D1);
    gemm8p<0><<<blocks, 512, 0, stream>>>(h1, w2q, b2, d_out, N, D1, D1);
}